// Round 7
// baseline (184.855 us; speedup 1.0000x reference)
//
#include <hip/hip_runtime.h>
#include <cstdint>

#define GH 10
#define GW 10

// Round 12: software-pipelined wave-private staging, de-risked.
// r11 ("container failed twice") used counted s_waitcnt vmcnt(14); the
// count assumed the compiler emitted exactly 14 vmem ops per chunk in
// program order -- fragile (compiler owns load scheduling). This version
// needs only vmcnt(0): per iteration, (1) drain -- chunk c's DMAs were
// issued BEFORE compute c-1, so they had a full compute phase to land and
// the wait is ~free; (2) issue chunk c+1's DMAs into the other buffer;
// (3) compute chunk c. Single-depth overlap preserved, zero counting
// assumptions, correct under any reordering (drain is total).
// Structure: block=128 (2 waves), each wave owns 128 consecutive samples
// = 4 chunks x 32, double-buffered 2x13.3KB wave-private LDS (53.2KB/blk,
// 3 blocks/CU). Staging = 13 x 1KB wave-DMAs (global_load_lds width 16);
// 13th overshoots 512B into the buffer pad (source clamped). Chunk loop
// is #pragma unroll 1 (one body copy: less I$, lower VGPR risk).
// Reduction bit-exact vs prior rounds: per-chunk 64-lane tree over the
// same 32 consecutive samples + serial c0..c3 add (== old wsum[0..3]) +
// one atomic per 128 samples. Per-sample arithmetic untouched (absmax 0).
__device__ __forceinline__ void gld_lds16(const float4* g, float4* l)
{
    __builtin_amdgcn_global_load_lds(
        (const __attribute__((address_space(1))) void*)g,
        (__attribute__((address_space(3))) void*)l,
        16 /*bytes: literal*/, 0 /*offset*/, 0 /*aux*/);
}

__device__ __forceinline__ float sample_loss(
    const float* __restrict__ sp, const int4 p, const int h)
{
    const int p0y = p.x, p0x = p.y, p1y = p.z, p1x = p.w;
    const int dy0 = abs(p0y - p1y), dx0 = abs(p0x - p1x);
    const int base0 = dy0 + dx0;
    const int idx0 = p0y * GW + p0x;
    const int idx1 = p1y * GW + p1x;

    const float rs = sp[idx0];            // LDS gathers, board resident
    const float re = sp[idx1];

    float adxf[10], inboxf[10];           // compile-time indexed -> regs
#pragma unroll
    for (int x = 0; x < 10; ++x) {
        const int a = abs(x - p0x) + abs(x - p1x) - dx0;
        adxf[x] = (float)a;
        inboxf[x] = (a == 0) ? 1.f : 0.f;
    }

    // ---- pass 1: stream own 5 rows from LDS; keep sums + mask only ----
    const float2* __restrict__ rp2 = (const float2*)(sp + h * 50);
    float sum_h = 0.f, sc_h = 0.f, box_h = 0.f;
    uint64_t mword = 0;                   // own 50-bit mask, bit = i*10+x
#pragma unroll
    for (int i = 0; i < 5; ++i) {
        const int y = 5 * h + i;
        float v[10];
#pragma unroll
        for (int j2 = 0; j2 < 5; ++j2) {
            const float2 tt = rp2[i * 5 + j2];
            v[2 * j2] = tt.x; v[2 * j2 + 1] = tt.y;
        }
        const float rowacc = ((v[0]+v[1])+(v[2]+v[3])) +
                             ((v[4]+v[5])+(v[6]+v[7])) + (v[8]+v[9]);
        sum_h += rowacc;
        const int ay = abs(y - p0y) + abs(y - p1y) - dy0;
        sc_h = fmaf((float)ay, rowacc, sc_h);
        float boxrow = 0.f;
        uint32_t rm = 0u;
#pragma unroll
        for (int x = 0; x < 10; ++x) {
            sc_h = fmaf(adxf[x], v[x], sc_h);
            boxrow = fmaf(inboxf[x], v[x], boxrow);
            // jnp.round half-to-even: for v in [0,1), round==1 <=> v>0.5
            rm |= (v[x] > 0.5f) ? (1u << x) : 0u;
        }
        box_h += (ay == 0) ? boxrow : 0.f;
        mword |= (uint64_t)rm << (10 * i);
    }
    const float sum_all = sum_h + __shfl_xor(sum_h, 1);
    const float sc      = sc_h  + __shfl_xor(sc_h, 1);
    const float boxSum  = box_h + __shfl_xor(box_h, 1);
    const uint64_t mo = (uint64_t)__shfl_xor((unsigned long long)mword, 1);
    const uint64_t mlo = h ? mo : mword;
    const uint64_t mhi = h ? mword : mo;

    // ---- flood fill: full board per lane (lockstep-duplicated = free) ----
    const uint64_t M50 = (1ull << 50) - 1;
    const uint64_t C0  = 0x10040100401ull;        // col-0 bit of 5 rows
    const uint64_t NC0 = M50 & ~C0;
    const uint64_t NC9 = M50 & ~(C0 << 9);
    uint64_t clo = 0, chi = 0;
    if (idx0 < 50) clo = 1ull << idx0; else chi = 1ull << (idx0 - 50);
#pragma unroll 1
    for (int it = 0; it < GH + GW; ++it) {        // cap 20 = reference
        const uint64_t hlo = clo | ((clo << 1) & NC0) | ((clo >> 1) & NC9);
        const uint64_t hhi = chi | ((chi << 1) & NC0) | ((chi >> 1) & NC9);
        uint64_t nlo = (hlo | (hlo << 10) | (hlo >> 10) | ((hhi & 0x3FFull) << 40)) & mlo;
        uint64_t nhi = (hhi | (hhi << 10) | (hhi >> 10) | (hlo >> 40)) & mhi;
        nlo |= clo; nhi |= chi;
        if (nlo == clo && nhi == chi) break;      // exit only at fixpoint
        clo = nlo; chi = nhi;
    }
    const int K = __popcll(clo) + __popcll(chi);

    // ---- S_T: re-stream own rows; bits via precomputed 5-bit fields ----
    // in_cl[y][x] = cluster bit (x*10+y); y = 5h+i -> pre-shift by 5h.
    const uint64_t wlo = clo >> (5 * h);
    const uint64_t whi = chi >> (5 * h);
    uint32_t fld[10];
#pragma unroll
    for (int x = 0; x < 10; ++x) {
        const uint64_t w = (x < 5) ? wlo : whi;        // compile-time sel
        fld[x] = (uint32_t)((w >> ((x % 5) * 10)) & 0x1Full);
    }
    float st_h = 0.f;
#pragma unroll
    for (int i = 0; i < 5; ++i) {
        float v[10];
#pragma unroll
        for (int j2 = 0; j2 < 5; ++j2) {
            const float2 tt = rp2[i * 5 + j2];
            v[2 * j2] = tt.x; v[2 * j2 + 1] = tt.y;
        }
#pragma unroll
        for (int x = 0; x < 10; ++x) {
            const uint32_t bit = (fld[x] >> i) & 1u;   // same bits as before
            st_h = fmaf((float)bit, v[x], st_h);
        }
    }
    const float S_T = st_h + __shfl_xor(st_h, 1);

    // ---- argmin (own 5 rows, then pair merge; first-flat-index ties) ----
    int bestd = 1000, bidx = 0;
    const uint64_t cw = h ? chi : clo;
#pragma unroll
    for (int i = 0; i < 5; ++i) {
        const int y = 5 * h + i;
        const uint32_t rb = (uint32_t)((cw >> (10 * i)) & 0x3FFull);
        const uint32_t left  = rb & ((2u << p1x) - 1);
        const uint32_t right = rb >> p1x;
        const int dl = left  ? (p1x - (31 - __builtin_clz(left))) : 1000;
        const int dr = right ? __builtin_ctz(right) : 1000;
        int dx, xx;
        if (dl <= dr) { dx = dl; xx = p1x - dl; }      // tie -> smaller col
        else          { dx = dr; xx = p1x + dr; }
        const int d = abs(y - p1y) + dx;
        if (rb && d < bestd) { bestd = d; bidx = y * GW + xx; }
    }
    {   // pair merge; tie -> smaller flat index
        const int od = __shfl_xor(bestd, 1);
        const int oi = __shfl_xor(bidx, 1);
        if (od < bestd || (od == bestd && oi < bidx)) { bestd = od; bidx = oi; }
    }

    // ---- epilogue (replicated; only h==0 contributes) ----
    const bool better = bestd < base0;
    const int ny = better ? bidx / 10 : p0y;
    const int nx = better ? bidx % 10 : p0x;
    const int gap = min(base0, bestd);

    int by = ny, bx = nx, bg = gap;
    const int oy = p1y - ny, ox = p1x - nx;
    auto upd = [&](bool cond, int cy, int cx) {
        const int d = abs(cy - p1y) + abs(cx - p1x);
        if (cond && (d < bg)) { by = cy; bx = cx; bg = d; }
    };
    upd(ox < 0,                     ny,     nx - 1);
    upd((ox < 0) && (ny != 0),      ny - 1, nx - 1);
    upd((ox < 0) && (ny != GH - 1), ny + 1, nx - 1);
    upd(ox > 0,                     ny,     nx + 1);
    upd((ox > 0) && (ny != 0),      ny - 1, nx + 1);
    upd((ox > 0) && (ny != GH - 1), ny + 1, nx + 1);
    upd(oy < 0,                     ny - 1, nx);
    upd(oy > 0,                     ny + 1, nx);
    const int ncy = min(max(by, 0), GH - 1);
    const int ncx = min(max(bx, 0), GW - 1);
    const float rn = sp[ncy * GW + ncx];  // board still resident in LDS

    const float csf = (float)K;
    const float nboxf = (float)((dy0 + 1) * (dx0 + 1));
    const float loss_start = (2.f - (rs + re)) * 1000.f;
    const float lon = 5.f * csf + 15.f * sum_all - 20.f * S_T;
    const float single_cell = 0.5f * sc + 20.f * (nboxf - boxSum);
    const float cpen = 12.f * csf * S_T;
    const float gap_pen = (float)gap * 300.f * (1.f - rn);
    return loss_start + lon + single_cell + cpen + gap_pen;
}

__global__ __launch_bounds__(128) void custom_loss_kernel(
    const float* __restrict__ result,
    const int* __restrict__ points,
    float* __restrict__ out,
    int B)
{
    // 2 waves x 2 buffers x 3328 floats (13312B = 12.5KB chunk + 512B DMA pad)
    __shared__ float lds[2 * 2 * 3328];
    const int tix = threadIdx.x;
    const int lane = tix & 63;
    const int wid = tix >> 6;
    const int h = tix & 1;                    // half: rows 5h..5h+4
    const int t = lane >> 1;                  // sample within chunk (0..31)

    const int waveBase = (blockIdx.x * 2 + wid) * 128;   // 128 samples/wave
    float* __restrict__ bufA = lds + wid * 6656;         // even chunks
    float* __restrict__ bufB = bufA + 3328;              // odd chunks

    const size_t total4 = (size_t)B * 25;
    const float4* __restrict__ g4 = (const float4*)result;
    const int4* __restrict__ pts4 = (const int4*)points;

    // stage chunk c (32 samples = 800 float4) via 13 x 1KB wave-DMAs; the
    // 13th overshoots 512B into the pad (per-lane source index clamped).
    auto stage = [&](int c, float* dstf) {
        float4* dst = (float4*)dstf;
        const size_t cb4 = ((size_t)waveBase + (size_t)c * 32) * 25;
#pragma unroll
        for (int k = 0; k < 13; ++k) {
            size_t gi = cb4 + (size_t)(k * 64 + lane);
            if (gi >= total4) gi = total4 - 1;
            gld_lds16(g4 + gi, dst + k * 64);
        }
    };
    auto ploadi = [&](int c) -> int4 {
        int si = waveBase + c * 32 + t;
        if (si >= B) si = B - 1;              // clamped: value unused if OOB
        return pts4[si];
    };

    // ---- prologue: chunk 0 in flight ----
    stage(0, bufA);
    int4 pts_next = ploadi(0);

    float wacc = 0.f;                         // serial c0..c3 == old wsum[0..3]
#pragma unroll 1
    for (int c = 0; c < 4; ++c) {
        // drain chunk c (issued one compute-phase ago -> wait is ~free)
        asm volatile("s_waitcnt vmcnt(0) lgkmcnt(0)" ::: "memory");
        const int4 p = pts_next;
        if (c < 3) {                          // issue chunk c+1 into the
            stage(c + 1, (c & 1) ? bufA : bufB);   // other buffer; stays in
            pts_next = ploadi(c + 1);              // flight under compute c
        }

        const float* __restrict__ sp =
            ((c & 1) ? bufB : bufA) + t * 100;
        const int s = waveBase + c * 32 + t;

        float loss = 0.f;
        if (s < B) {
            loss = sample_loss(sp, p, h);
            if (h != 0) loss = 0.f;           // one contribution per sample
        }
        // per-chunk 64-lane tree: identical order to prior rounds' per-wave
        // tree over the same 32 consecutive samples -> bit-identical sums
#pragma unroll
        for (int off = 32; off > 0; off >>= 1)
            loss += __shfl_down(loss, off);
        wacc += loss;                         // only lane 0's value is used
    }

    if (lane == 0) atomicAdd(out, wacc);      // one atomic per 128 samples
}

extern "C" void kernel_launch(void* const* d_in, const int* in_sizes, int n_in,
                              void* d_out, int out_size, void* d_ws, size_t ws_size,
                              hipStream_t stream)
{
    const float* result = (const float*)d_in[0];
    const int* points   = (const int*)d_in[1];
    float* out = (float*)d_out;
    const int B = in_sizes[0] / 100;
    hipMemsetAsync(out, 0, sizeof(float), stream);   // harness poisons d_out
    const int block = 128;                            // 2 waves; 256 samples/blk
    const int grid = (B + 255) / 256;
    custom_loss_kernel<<<grid, block, 0, stream>>>(result, points, out, B);
}